// Round 18
// baseline (298.478 us; speedup 1.0000x reference)
//
#include <hip/hip_runtime.h>
#include <hip/hip_bf16.h>

#define N_NODES 100000
#define N_EDGES 1600000
#define IN_CH 50
#define NPB 512                                   // nodes per bucket (dst >> 9)
#define NB ((N_NODES + NPB - 1) / NPB)            // 196 buckets
#define CAPLOG 14                                 // 16384 slots/bucket (max ~8.6K used)
#define EPB 4096
#define NBLK_A ((N_EDGES + EPB - 1) / EPB)        // 391 bin blocks
#define PAD_BLOCKS ((N_NODES * 64) / 1024)        // 6250 pad blocks (1024 thr)

typedef _Float16 h2 __attribute__((ext_vector_type(2)));
typedef __fp16   fp16x2 __attribute__((ext_vector_type(2)));

__device__ __forceinline__ h2 ash2(unsigned u) {
    union { unsigned u; h2 h; } c; c.u = u; return c.h;
}
__device__ __forceinline__ unsigned packh2(float a, float b) {
    union { fp16x2 p; unsigned u; } c;
    c.p = __builtin_amdgcn_cvt_pkrtz(a, b);
    return c.u;
}
__device__ __forceinline__ float bf16lo(unsigned u) {   // low bf16 of pair
    return __uint_as_float(u << 16);
}
__device__ __forceinline__ float bf16hi(unsigned u) {   // high bf16 of pair
    return __uint_as_float(u & 0xffff0000u);
}

// ---- 1. bin edges into fixed-capacity buckets (+ pad x->xb) (+ last block: pack W) ----
__global__ __launch_bounds__(1024) void bin_pad_kernel(
    const int* __restrict__ src, const int* __restrict__ dst,
    int* __restrict__ cursor_rel, unsigned* __restrict__ binned,
    const float* __restrict__ x, unsigned short* __restrict__ xb,
    const float* __restrict__ W1, const float* __restrict__ W2,
    unsigned* __restrict__ Wp1, unsigned* __restrict__ Wp2) {
    if (blockIdx.x == NBLK_A + PAD_BLOCKS) {       // weight-pack block
        int t = threadIdx.x;
        for (int idx = t; idx < 25 * 64; idx += 1024) {
            int k2 = idx >> 6, j = idx & 63;
            Wp1[k2 * 64 + j] =
                packh2(W1[(2 * k2) * 64 + j], W1[(2 * k2 + 1) * 64 + j]);
            Wp1[(25 + k2) * 64 + j] =
                packh2(W1[(IN_CH + 2 * k2) * 64 + j], W1[(IN_CH + 2 * k2 + 1) * 64 + j]);
        }
        for (int idx = t; idx < 64 * 32; idx += 1024) {
            int k2 = idx >> 5, j = idx & 31;
            Wp2[idx] = packh2(W2[(2 * k2) * 32 + j], W2[(2 * k2 + 1) * 32 + j]);
        }
        return;
    }
    if (blockIdx.x >= NBLK_A) {                    // pad lane
        int t = (blockIdx.x - NBLK_A) * 1024 + threadIdx.x;  // < N_NODES*64
        int n = t >> 6, c = t & 63;
        float v = (c < IN_CH) ? x[n * IN_CH + c] : 0.0f;
        __hip_bfloat16 hb = __float2bfloat16(v);
        xb[t] = *(unsigned short*)&hb;
        return;
    }
    __shared__ int bc[NB];
    __shared__ int boff[NB];
    int t = threadIdx.x;
    if (t < NB) bc[t] = 0;
    __syncthreads();
    int e0 = blockIdx.x * EPB;
    int e1 = min(e0 + EPB, N_EDGES);
    for (int i = e0 + t; i < e1; i += 1024)
        atomicAdd(&bc[dst[i] >> 9], 1);
    __syncthreads();
    if (t < NB) {
        int v = bc[t];
        int rel = v ? atomicAdd(&cursor_rel[t], v) : 0;
        boff[t] = (t << CAPLOG) + rel;
        bc[t] = 0;                                 // reuse as local cursor
    }
    __syncthreads();
    for (int i = e0 + t; i < e1; i += 1024) {
        int d = dst[i];
        int b = d >> 9;
        int k = atomicAdd(&bc[b], 1);
        binned[boff[b] + k] = ((unsigned)(d & 511) << 17) | (unsigned)src[i];
    }
}

// ---- 2. per-bucket fine sort (u32 payload) -> cnt, row_start, csr_src ----
__global__ __launch_bounds__(1024) void bucket_fine(
    const unsigned* __restrict__ binned, const int* __restrict__ cursor_rel,
    int* __restrict__ cnt, int* __restrict__ row_start, int* __restrict__ csr_src) {
    __shared__ int lcnt[NPB];
    __shared__ int lofs[NPB];
    __shared__ int sc[NPB];
    int t = threadIdx.x;
    int b = blockIdx.x;
    int nbase = b * NPB;
    int bbase = b << CAPLOG;
    int ecnt  = cursor_rel[b];
    if (t < NPB) lcnt[t] = 0;
    __syncthreads();
    for (int i = t; i < ecnt; i += 1024)
        atomicAdd(&lcnt[(binned[bbase + i] >> 17) & 511], 1);
    __syncthreads();
    int v = (t < NPB) ? lcnt[t] : 0;
    if (t < NPB) sc[t] = v;
    __syncthreads();
    for (int off = 1; off < NPB; off <<= 1) {      // Hillis-Steele over 512
        int tmp = (t < NPB && t >= off) ? sc[t - off] : 0;
        __syncthreads();
        if (t < NPB) sc[t] += tmp;
        __syncthreads();
    }
    if (t < NPB) {
        int excl = sc[t] - v;
        lofs[t] = excl;
        int n = nbase + t;
        if (n < N_NODES) { cnt[n] = v; row_start[n] = bbase + excl; }
    }
    __syncthreads();
    for (int i = t; i < ecnt; i += 1024) {
        unsigned p = binned[bbase + i];
        int d = (int)((p >> 17) & 511);
        int k = atomicAdd(&lofs[d], 1);
        csr_src[bbase + k] = (int)(p & 0x1FFFFu);
    }
}

// unpack 8 bf16 from uint4, predicated fma into acc[0..8)
__device__ __forceinline__ void upadd8(float* a, uint4 v, float p) {
    a[0] = fmaf(p, __uint_as_float(v.x << 16), a[0]);
    a[1] = fmaf(p, __uint_as_float(v.x & 0xffff0000u), a[1]);
    a[2] = fmaf(p, __uint_as_float(v.y << 16), a[2]);
    a[3] = fmaf(p, __uint_as_float(v.y & 0xffff0000u), a[3]);
    a[4] = fmaf(p, __uint_as_float(v.z << 16), a[4]);
    a[5] = fmaf(p, __uint_as_float(v.z & 0xffff0000u), a[5]);
    a[6] = fmaf(p, __uint_as_float(v.w << 16), a[6]);
    a[7] = fmaf(p, __uint_as_float(v.w & 0xffff0000u), a[7]);
}

// wave-local LDS fence: LDS ops of one wave complete in order; no block barrier.
#define WAVE_LDS_FENCE() __asm__ volatile("s_waitcnt lgkmcnt(0)" ::: "memory")

// Gather-mean of 4 nodes per wave, chains interleaved (proven R7/R10/R13 shape).
__device__ __forceinline__ void gather4(
    const unsigned short* __restrict__ featb, const int* __restrict__ csr_src,
    const int* __restrict__ row_start, const int* __restrict__ cnt,
    int nb, int lane, float acc[4][8]) {
    int g  = lane >> 3;
    int cw = (lane & 7) * 8;
    int start[4], deg[4], sv[4];
    int dmax = 0;
    #pragma unroll
    for (int i = 0; i < 4; ++i) {
        start[i] = row_start[nb + i];
        deg[i]   = cnt[nb + i];
        dmax = max(dmax, deg[i]);
        #pragma unroll
        for (int c = 0; c < 8; ++c) acc[i][c] = 0.f;
    }
    #pragma unroll
    for (int i = 0; i < 4; ++i)
        sv[i] = (lane < deg[i]) ? csr_src[start[i] + lane] : 0;

    #pragma unroll
    for (int cb = 0; cb < 64; cb += 16) {
        if (cb >= dmax) break;                 // wave-uniform
        #pragma unroll
        for (int i = 0; i < 4; ++i) {
            int rem = deg[i] - cb;
            if (rem > 0) {                     // wave-uniform
                int s0 = __shfl(sv[i], cb + g);
                int s1 = __shfl(sv[i], cb + 8 + g);
                float p0 = (g < rem) ? 1.f : 0.f;
                float p1 = (g + 8 < rem) ? 1.f : 0.f;
                uint4 v0 = *(const uint4*)(featb + s0 * 64 + cw);
                uint4 v1 = *(const uint4*)(featb + s1 * 64 + cw);
                upadd8(acc[i], v0, p0);
                upadd8(acc[i], v1, p1);
            }
        }
    }
    if (dmax > 64) {                           // rare tail
        for (int i = 0; i < 4; ++i) {
            for (int c0 = 64; c0 < deg[i]; c0 += 64) {
                int rem = deg[i] - c0; if (rem > 64) rem = 64;
                int sx = (lane < rem) ? csr_src[start[i] + c0 + lane] : 0;
                for (int cb = 0; cb < rem; cb += 16) {
                    int s0 = __shfl(sx, cb + g);
                    int s1 = __shfl(sx, cb + 8 + g);
                    float p0 = (cb + g < rem) ? 1.f : 0.f;
                    float p1 = (cb + 8 + g < rem) ? 1.f : 0.f;
                    uint4 v0 = *(const uint4*)(featb + s0 * 64 + cw);
                    uint4 v1 = *(const uint4*)(featb + s1 * 64 + cw);
                    upadd8(acc[i], v0, p0);
                    upadd8(acc[i], v1, p1);
                }
            }
        }
    }
    #pragma unroll
    for (int i = 0; i < 4; ++i) {
        float inv = 1.0f / fmaxf((float)deg[i], 1.0f);
        #pragma unroll
        for (int c = 0; c < 8; ++c) {
            float t = acc[i][c];
            t += __shfl_xor(t, 8);
            t += __shfl_xor(t, 16);
            t += __shfl_xor(t, 32);
            acc[i][c] = t * inv;
        }
    }
}

// ---- 3. layer 1: 1024 thr (16 waves); per wave: gather(xb) + dot2 GEMM(100x64) ----
__global__ __launch_bounds__(1024) void layer1_fused(
    const unsigned short* __restrict__ xb,
    const int* __restrict__ csr_src, const int* __restrict__ row_start,
    const int* __restrict__ cnt, const unsigned* __restrict__ Wp1,
    const float* __restrict__ b1, unsigned short* __restrict__ h1b) {
    int wv   = threadIdx.x >> 6;               // 0..15
    int lane = threadIdx.x & 63;
    int nb   = (blockIdx.x * 16 + wv) * 4;     // 64 nodes/block
    if (nb >= N_NODES) return;                 // wave-uniform; no block barrier below

    float acc[4][8];
    gather4(xb, csr_src, row_start, cnt, nb, lane, acc);

    __shared__ __align__(16) unsigned featH[16][4][60];  // 15.4 KB
    const unsigned* xb32 = (const unsigned*)xb;          // bf16 pairs
    #pragma unroll
    for (int i = 0; i < 4; ++i) {
        if (lane < 25) {
            unsigned u = xb32[((nb + i) << 5) + lane];   // ch 2*lane, 2*lane+1
            featH[wv][i][lane] = packh2(bf16lo(u), bf16hi(u));
        }
        if (lane < 8) {
            uint4 m;
            m.x = packh2(acc[i][0], acc[i][1]);
            m.y = packh2(acc[i][2], acc[i][3]);
            m.z = packh2(acc[i][4], acc[i][5]);
            m.w = packh2(acc[i][6], acc[i][7]);
            *(uint4*)&featH[wv][i][28 + lane * 4] = m;   // mean pairs lane*4..+3
        }
    }
    WAVE_LDS_FENCE();

    float ao[4];
    float bb = b1[lane];
    #pragma unroll
    for (int i = 0; i < 4; ++i) ao[i] = bb;
    #pragma unroll 5
    for (int k2 = 0; k2 < 25; ++k2) {
        h2 w = ash2(Wp1[k2 * 64 + lane]);      // lanes coalesced
        #pragma unroll
        for (int i = 0; i < 4; ++i)
            ao[i] = __builtin_amdgcn_fdot2(ash2(featH[wv][i][k2]), w, ao[i], false);
    }
    #pragma unroll 5
    for (int k2 = 0; k2 < 25; ++k2) {
        h2 w = ash2(Wp1[(25 + k2) * 64 + lane]);
        #pragma unroll
        for (int i = 0; i < 4; ++i)
            ao[i] = __builtin_amdgcn_fdot2(ash2(featH[wv][i][28 + k2]), w, ao[i], false);
    }
    #pragma unroll
    for (int i = 0; i < 4; ++i) {
        float r = fmaxf(ao[i], 0.f);
        __hip_bfloat16 hb = __float2bfloat16(r);
        h1b[((nb + i) << 6) + lane] = *(unsigned short*)&hb;
    }
}

// ---- 4. layers 2+3: 1024 thr (16 waves); gather(h1b) + dot2 GEMM(128x32) + dot(W3) ----
__global__ __launch_bounds__(1024) void layer23_fused(
    const unsigned short* __restrict__ h1b,
    const int* __restrict__ csr_src, const int* __restrict__ row_start,
    const int* __restrict__ cnt, const unsigned* __restrict__ Wp2,
    const float* __restrict__ b2, const float* __restrict__ W3,
    const float* __restrict__ b3, float* __restrict__ out) {
    int wv   = threadIdx.x >> 6;
    int lane = threadIdx.x & 63;
    int nb   = (blockIdx.x * 16 + wv) * 4;
    if (nb >= N_NODES) return;                 // wave-uniform; no block barrier below

    float acc[4][8];
    gather4(h1b, csr_src, row_start, cnt, nb, lane, acc);

    __shared__ __align__(16) unsigned featH[16][4][64];  // 16.4 KB
    const unsigned* h32 = (const unsigned*)h1b;          // bf16 pairs
    #pragma unroll
    for (int i = 0; i < 4; ++i) {
        if (lane < 32) {
            unsigned u = h32[((nb + i) << 5) + lane];
            featH[wv][i][lane] = packh2(bf16lo(u), bf16hi(u));
        }
        if (lane < 8) {
            uint4 m;
            m.x = packh2(acc[i][0], acc[i][1]);
            m.y = packh2(acc[i][2], acc[i][3]);
            m.z = packh2(acc[i][4], acc[i][5]);
            m.w = packh2(acc[i][6], acc[i][7]);
            *(uint4*)&featH[wv][i][32 + lane * 4] = m;
        }
    }
    WAVE_LDS_FENCE();

    int hh = lane >> 5;                        // half-wave id: nodes nb+hh, nb+2+hh
    int j  = lane & 31;
    float a0 = b2[j], a1 = a0;
    #pragma unroll 8
    for (int k2 = 0; k2 < 64; ++k2) {
        h2 w = ash2(Wp2[k2 * 32 + j]);         // lanes coalesced
        a0 = __builtin_amdgcn_fdot2(ash2(featH[wv][hh][k2]),     w, a0, false);
        a1 = __builtin_amdgcn_fdot2(ash2(featH[wv][2 + hh][k2]), w, a1, false);
    }
    float w3 = W3[j];
    float c3 = b3[0];
    float v0 = fmaxf(a0, 0.f) * w3;
    float v1 = fmaxf(a1, 0.f) * w3;
    #pragma unroll
    for (int off = 1; off <= 16; off <<= 1) {
        v0 += __shfl_xor(v0, off);
        v1 += __shfl_xor(v1, off);
    }
    if (j == 0) {
        out[nb + hh]     = v0 + c3;
        out[nb + 2 + hh] = v1 + c3;
    }
}

extern "C" void kernel_launch(void* const* d_in, const int* in_sizes, int n_in,
                              void* d_out, int out_size, void* d_ws, size_t ws_size,
                              hipStream_t stream) {
    const float* x   = (const float*)d_in[0];
    const int*   ei  = (const int*)d_in[1];
    const int*   src = ei;
    const int*   dst = ei + N_EDGES;
    const float* W1  = (const float*)d_in[2];
    const float* b1  = (const float*)d_in[3];
    const float* W2  = (const float*)d_in[4];
    const float* b2  = (const float*)d_in[5];
    const float* W3  = (const float*)d_in[6];
    const float* b3  = (const float*)d_in[7];
    float* out = (float*)d_out;

    // ws (~52 MB): cursor_rel | cnt | row_start | binned u32[NB<<14] 12.85MB |
    //   csr_src[NB<<14] 12.85MB | xb bf16 12.8MB | h1b bf16 12.8MB | Wp1 12.8KB | Wp2 8KB
    char* ws = (char*)d_ws;
    auto align = [](size_t v) { return (v + 255) & ~(size_t)255; };
    size_t o = 0;
    int* cursor_rel = (int*)(ws + o); o = align(o + 256 * 4);
    int* cnt       = (int*)(ws + o); o = align(o + (size_t)N_NODES * 4);
    int* row_start = (int*)(ws + o); o = align(o + (size_t)N_NODES * 4);
    unsigned* binned = (unsigned*)(ws + o); o = align(o + ((size_t)NB << CAPLOG) * 4);
    int* csr_src   = (int*)(ws + o); o = align(o + ((size_t)NB << CAPLOG) * 4);
    unsigned short* xb  = (unsigned short*)(ws + o); o = align(o + (size_t)N_NODES * 64 * 2);
    unsigned short* h1b = (unsigned short*)(ws + o); o = align(o + (size_t)N_NODES * 64 * 2);
    unsigned* Wp1 = (unsigned*)(ws + o); o = align(o + 50 * 64 * 4);
    unsigned* Wp2 = (unsigned*)(ws + o); o = align(o + 64 * 32 * 4);

    (void)hipMemsetAsync(cursor_rel, 0, 256 * sizeof(int), stream);

    bin_pad_kernel<<<NBLK_A + PAD_BLOCKS + 1, 1024, 0, stream>>>(
        src, dst, cursor_rel, binned, x, xb, W1, W2, Wp1, Wp2);
    bucket_fine<<<NB, 1024, 0, stream>>>(binned, cursor_rel, cnt, row_start, csr_src);

    int nodes_per_blk = 64;                        // 16 waves x 4 nodes
    int lgrid = (N_NODES + nodes_per_blk - 1) / nodes_per_blk;   // 1563
    layer1_fused<<<lgrid, 1024, 0, stream>>>(xb, csr_src, row_start, cnt,
                                             Wp1, b1, h1b);
    layer23_fused<<<lgrid, 1024, 0, stream>>>(h1b, csr_src, row_start, cnt,
                                              Wp2, b2, W3, b3, out);
}

// Round 19
// 254.304 us; speedup vs baseline: 1.1737x; 1.1737x over previous
//
#include <hip/hip_runtime.h>
#include <hip/hip_bf16.h>

#define N_NODES 100000
#define N_EDGES 1600000
#define IN_CH 50
#define NPB 256                                   // nodes per bucket (dst >> 8)
#define NB ((N_NODES + NPB - 1) / NPB)            // 391 buckets
#define CAPLOG 13                                 // 8192 slots/bucket (max ~4.4K used)
#define EPB 4096
#define NBLK_A ((N_EDGES + EPB - 1) / EPB)        // 391 bin blocks
#define PAD_BLOCKS ((N_NODES * 64) / 1024)        // 6250 pad blocks (1024 thr)

// ---- 1. bin edges into fixed-capacity buckets (+ extra blocks: pad x->xb bf16) ----
// cursor_rel[b] is RELATIVE (starts 0 via memset); slot = (b<<CAPLOG) + rel.
__global__ __launch_bounds__(1024) void bin_pad_kernel(
    const int* __restrict__ src, const int* __restrict__ dst,
    int* __restrict__ cursor_rel, unsigned* __restrict__ binned,
    const float* __restrict__ x, unsigned short* __restrict__ xb) {
    if (blockIdx.x >= NBLK_A) {                    // pad lane
        int t = (blockIdx.x - NBLK_A) * 1024 + threadIdx.x;  // < N_NODES*64
        int n = t >> 6, c = t & 63;
        float v = (c < IN_CH) ? x[n * IN_CH + c] : 0.0f;
        __hip_bfloat16 hb = __float2bfloat16(v);
        xb[t] = *(unsigned short*)&hb;
        return;
    }
    __shared__ int bc[NB];
    __shared__ int boff[NB];
    int t = threadIdx.x;
    if (t < NB) bc[t] = 0;
    __syncthreads();
    int e0 = blockIdx.x * EPB;
    int e1 = min(e0 + EPB, N_EDGES);
    for (int i = e0 + t; i < e1; i += 1024)
        atomicAdd(&bc[dst[i] >> 8], 1);
    __syncthreads();
    if (t < NB) {
        int v = bc[t];
        int rel = v ? atomicAdd(&cursor_rel[t], v) : 0;
        boff[t] = (t << CAPLOG) + rel;
        bc[t] = 0;                                 // reuse as local cursor
    }
    __syncthreads();
    for (int i = e0 + t; i < e1; i += 1024) {
        int d = dst[i];
        int b = d >> 8;
        int k = atomicAdd(&bc[b], 1);
        binned[boff[b] + k] = ((unsigned)(d & 255) << 17) | (unsigned)src[i];
    }
}

// ---- 2. per-bucket fine sort (u32 payload) -> cnt, row_start, csr_src ----
// 391 blocks x 1024 threads: ~1.5 blocks/CU.
__global__ __launch_bounds__(1024) void bucket_fine(
    const unsigned* __restrict__ binned, const int* __restrict__ cursor_rel,
    int* __restrict__ cnt, int* __restrict__ row_start, int* __restrict__ csr_src) {
    __shared__ int lcnt[NPB];
    __shared__ int lofs[NPB];
    __shared__ int sc[NPB];
    int t = threadIdx.x;
    int b = blockIdx.x;
    int nbase = b * NPB;
    int bbase = b << CAPLOG;
    int ecnt  = cursor_rel[b];
    if (t < NPB) lcnt[t] = 0;
    __syncthreads();
    for (int i = t; i < ecnt; i += 1024)
        atomicAdd(&lcnt[(binned[bbase + i] >> 17) & 255], 1);
    __syncthreads();
    int v = (t < NPB) ? lcnt[t] : 0;
    if (t < NPB) sc[t] = v;
    __syncthreads();
    for (int off = 1; off < NPB; off <<= 1) {      // Hillis-Steele over 256
        int tmp = (t < NPB && t >= off) ? sc[t - off] : 0;
        __syncthreads();
        if (t < NPB) sc[t] += tmp;
        __syncthreads();
    }
    if (t < NPB) {
        int excl = sc[t] - v;
        lofs[t] = excl;
        int n = nbase + t;
        if (n < N_NODES) { cnt[n] = v; row_start[n] = bbase + excl; }
    }
    __syncthreads();
    for (int i = t; i < ecnt; i += 1024) {
        unsigned p = binned[bbase + i];
        int d = (int)((p >> 17) & 255);
        int k = atomicAdd(&lofs[d], 1);
        csr_src[bbase + k] = (int)(p & 0x1FFFFu);
    }
}

// unpack 8 bf16 from uint4, predicated fma into acc[0..8)
__device__ __forceinline__ void upadd8(float* a, uint4 v, float p) {
    a[0] = fmaf(p, __uint_as_float(v.x << 16), a[0]);
    a[1] = fmaf(p, __uint_as_float(v.x & 0xffff0000u), a[1]);
    a[2] = fmaf(p, __uint_as_float(v.y << 16), a[2]);
    a[3] = fmaf(p, __uint_as_float(v.y & 0xffff0000u), a[3]);
    a[4] = fmaf(p, __uint_as_float(v.z << 16), a[4]);
    a[5] = fmaf(p, __uint_as_float(v.z & 0xffff0000u), a[5]);
    a[6] = fmaf(p, __uint_as_float(v.w << 16), a[6]);
    a[7] = fmaf(p, __uint_as_float(v.w & 0xffff0000u), a[7]);
}

// wave-local LDS fence: LDS ops of one wave complete in order; no block barrier.
#define WAVE_LDS_FENCE() __asm__ volatile("s_waitcnt lgkmcnt(0)" ::: "memory")

// Gather-mean of 4 nodes per wave, chains interleaved (proven R7/R10/R13 shape).
__device__ __forceinline__ void gather4(
    const unsigned short* __restrict__ featb, const int* __restrict__ csr_src,
    const int* __restrict__ row_start, const int* __restrict__ cnt,
    int nb, int lane, float acc[4][8]) {
    int g  = lane >> 3;
    int cw = (lane & 7) * 8;
    int start[4], deg[4], sv[4];
    int dmax = 0;
    #pragma unroll
    for (int i = 0; i < 4; ++i) {
        start[i] = row_start[nb + i];
        deg[i]   = cnt[nb + i];
        dmax = max(dmax, deg[i]);
        #pragma unroll
        for (int c = 0; c < 8; ++c) acc[i][c] = 0.f;
    }
    #pragma unroll
    for (int i = 0; i < 4; ++i)
        sv[i] = (lane < deg[i]) ? csr_src[start[i] + lane] : 0;

    #pragma unroll
    for (int cb = 0; cb < 64; cb += 16) {
        if (cb >= dmax) break;                 // wave-uniform
        #pragma unroll
        for (int i = 0; i < 4; ++i) {
            int rem = deg[i] - cb;
            if (rem > 0) {                     // wave-uniform
                int s0 = __shfl(sv[i], cb + g);
                int s1 = __shfl(sv[i], cb + 8 + g);
                float p0 = (g < rem) ? 1.f : 0.f;
                float p1 = (g + 8 < rem) ? 1.f : 0.f;
                uint4 v0 = *(const uint4*)(featb + s0 * 64 + cw);
                uint4 v1 = *(const uint4*)(featb + s1 * 64 + cw);
                upadd8(acc[i], v0, p0);
                upadd8(acc[i], v1, p1);
            }
        }
    }
    if (dmax > 64) {                           // rare tail
        for (int i = 0; i < 4; ++i) {
            for (int c0 = 64; c0 < deg[i]; c0 += 64) {
                int rem = deg[i] - c0; if (rem > 64) rem = 64;
                int sx = (lane < rem) ? csr_src[start[i] + c0 + lane] : 0;
                for (int cb = 0; cb < rem; cb += 16) {
                    int s0 = __shfl(sx, cb + g);
                    int s1 = __shfl(sx, cb + 8 + g);
                    float p0 = (cb + g < rem) ? 1.f : 0.f;
                    float p1 = (cb + 8 + g < rem) ? 1.f : 0.f;
                    uint4 v0 = *(const uint4*)(featb + s0 * 64 + cw);
                    uint4 v1 = *(const uint4*)(featb + s1 * 64 + cw);
                    upadd8(acc[i], v0, p0);
                    upadd8(acc[i], v1, p1);
                }
            }
        }
    }
    #pragma unroll
    for (int i = 0; i < 4; ++i) {
        float inv = 1.0f / fmaxf((float)deg[i], 1.0f);
        #pragma unroll
        for (int c = 0; c < 8; ++c) {
            float t = acc[i][c];
            t += __shfl_xor(t, 8);
            t += __shfl_xor(t, 16);
            t += __shfl_xor(t, 32);
            acc[i][c] = t * inv;
        }
    }
}

__device__ __forceinline__ float bf16u(unsigned short u) {
    return __uint_as_float(((unsigned)u) << 16);
}

// ---- 3. layer 1 (R13/R15-proven): 4 nodes/wave; gather(xb) + scalar-broadcast GEMM ----
__global__ __launch_bounds__(256) void layer1_fused(
    const unsigned short* __restrict__ xb,
    const int* __restrict__ csr_src, const int* __restrict__ row_start,
    const int* __restrict__ cnt, const float* __restrict__ W1,
    const float* __restrict__ b1, unsigned short* __restrict__ h1b) {
    int wv   = threadIdx.x >> 6;
    int lane = threadIdx.x & 63;
    int nb   = (blockIdx.x * 4 + wv) * 4;      // N_NODES % 16 == 0

    float acc[4][8];
    gather4(xb, csr_src, row_start, cnt, nb, lane, acc);

    __shared__ __align__(16) float selfF[4][4][64];
    __shared__ __align__(16) float meanF[4][4][64];
    #pragma unroll
    for (int i = 0; i < 4; ++i) {
        selfF[wv][i][lane] = bf16u(xb[((nb + i) << 6) + lane]);
        if (lane < 8) {
            *(float4*)&meanF[wv][i][lane * 8] =
                make_float4(acc[i][0], acc[i][1], acc[i][2], acc[i][3]);
            *(float4*)&meanF[wv][i][lane * 8 + 4] =
                make_float4(acc[i][4], acc[i][5], acc[i][6], acc[i][7]);
        }
    }
    WAVE_LDS_FENCE();

    float ao[4];
    float bb = b1[lane];
    #pragma unroll
    for (int i = 0; i < 4; ++i) ao[i] = bb;
    #pragma unroll
    for (int k = 0; k < IN_CH; ++k) {
        float w = W1[k * 64 + lane];           // lanes coalesced, reused x4
        #pragma unroll
        for (int i = 0; i < 4; ++i) ao[i] = fmaf(selfF[wv][i][k], w, ao[i]);
    }
    #pragma unroll
    for (int k = 0; k < IN_CH; ++k) {
        float w = W1[(IN_CH + k) * 64 + lane];
        #pragma unroll
        for (int i = 0; i < 4; ++i) ao[i] = fmaf(meanF[wv][i][k], w, ao[i]);
    }
    #pragma unroll
    for (int i = 0; i < 4; ++i) {
        float r = fmaxf(ao[i], 0.f);
        __hip_bfloat16 hb = __float2bfloat16(r);
        h1b[((nb + i) << 6) + lane] = *(unsigned short*)&hb;
    }
}

// ---- 4. layers 2+3 (R13/R15-proven): gather(h1b) + scalar-broadcast GEMM + dot(W3) ----
__global__ __launch_bounds__(256) void layer23_fused(
    const unsigned short* __restrict__ h1b,
    const int* __restrict__ csr_src, const int* __restrict__ row_start,
    const int* __restrict__ cnt, const float* __restrict__ W2,
    const float* __restrict__ b2, const float* __restrict__ W3,
    const float* __restrict__ b3, float* __restrict__ out) {
    int wv   = threadIdx.x >> 6;
    int lane = threadIdx.x & 63;
    int nb   = (blockIdx.x * 4 + wv) * 4;

    float acc[4][8];
    gather4(h1b, csr_src, row_start, cnt, nb, lane, acc);

    __shared__ __align__(16) float featL[4][4][128];   // [0,64)=self, [64,128)=mean
    #pragma unroll
    for (int i = 0; i < 4; ++i) {
        featL[wv][i][lane] = bf16u(h1b[((nb + i) << 6) + lane]);
        if (lane < 8) {
            *(float4*)&featL[wv][i][64 + lane * 8] =
                make_float4(acc[i][0], acc[i][1], acc[i][2], acc[i][3]);
            *(float4*)&featL[wv][i][64 + lane * 8 + 4] =
                make_float4(acc[i][4], acc[i][5], acc[i][6], acc[i][7]);
        }
    }
    WAVE_LDS_FENCE();

    int hh = lane >> 5;                        // half-wave id: nodes nb+hh, nb+2+hh
    int j  = lane & 31;
    float a0 = b2[j], a1 = a0;
    #pragma unroll
    for (int k = 0; k < 128; ++k) {
        float w = W2[k * 32 + j];              // lanes coalesced, reused x2
        a0 = fmaf(featL[wv][hh][k],     w, a0);
        a1 = fmaf(featL[wv][2 + hh][k], w, a1);
    }
    float w3 = W3[j];
    float c3 = b3[0];
    float v0 = fmaxf(a0, 0.f) * w3;
    float v1 = fmaxf(a1, 0.f) * w3;
    #pragma unroll
    for (int off = 1; off <= 16; off <<= 1) {
        v0 += __shfl_xor(v0, off);
        v1 += __shfl_xor(v1, off);
    }
    if (j == 0) {
        out[nb + hh]     = v0 + c3;
        out[nb + 2 + hh] = v1 + c3;
    }
}

extern "C" void kernel_launch(void* const* d_in, const int* in_sizes, int n_in,
                              void* d_out, int out_size, void* d_ws, size_t ws_size,
                              hipStream_t stream) {
    const float* x   = (const float*)d_in[0];
    const int*   ei  = (const int*)d_in[1];
    const int*   src = ei;
    const int*   dst = ei + N_EDGES;
    const float* W1  = (const float*)d_in[2];
    const float* b1  = (const float*)d_in[3];
    const float* W2  = (const float*)d_in[4];
    const float* b2  = (const float*)d_in[5];
    const float* W3  = (const float*)d_in[6];
    const float* b3  = (const float*)d_in[7];
    float* out = (float*)d_out;

    // ws (~52 MB): cursor_rel[512] | cnt | row_start | binned u32[NB<<13] 12.8MB |
    //   csr_src[NB<<13] 12.8MB | xb bf16 12.8MB | h1b bf16 12.8MB
    char* ws = (char*)d_ws;
    auto align = [](size_t v) { return (v + 255) & ~(size_t)255; };
    size_t o = 0;
    int* cursor_rel = (int*)(ws + o); o = align(o + 512 * 4);
    int* cnt       = (int*)(ws + o); o = align(o + (size_t)N_NODES * 4);
    int* row_start = (int*)(ws + o); o = align(o + (size_t)N_NODES * 4);
    unsigned* binned = (unsigned*)(ws + o); o = align(o + ((size_t)NB << CAPLOG) * 4);
    int* csr_src   = (int*)(ws + o); o = align(o + ((size_t)NB << CAPLOG) * 4);
    unsigned short* xb  = (unsigned short*)(ws + o); o = align(o + (size_t)N_NODES * 64 * 2);
    unsigned short* h1b = (unsigned short*)(ws + o); o = align(o + (size_t)N_NODES * 64 * 2);

    (void)hipMemsetAsync(cursor_rel, 0, 512 * sizeof(int), stream);

    bin_pad_kernel<<<NBLK_A + PAD_BLOCKS, 1024, 0, stream>>>(src, dst, cursor_rel,
                                                             binned, x, xb);
    bucket_fine<<<NB, 1024, 0, stream>>>(binned, cursor_rel, cnt, row_start, csr_src);

    layer1_fused<<<N_NODES / 16, 256, 0, stream>>>(xb, csr_src, row_start, cnt,
                                                   W1, b1, h1b);
    layer23_fused<<<N_NODES / 16, 256, 0, stream>>>(h1b, csr_src, row_start, cnt,
                                                    W2, b2, W3, b3, out);
}